// Round 1
// baseline (321.952 us; speedup 1.0000x reference)
//
#include <hip/hip_runtime.h>
#include <stdint.h>

#define HH 128
#define WW 128
#define HW 16384
#define NI 64
#define NM 256
#define WORDS 256  // 16384 / 64 bits

// ---------------- Matrix NMS ----------------

// Pack binary masks into bits: packed[word][mask] layout for coalesced column reads.
__global__ __launch_bounds__(256) void pack_kernel(const float* __restrict__ seg,
                                                   unsigned long long* __restrict__ packed) {
    int i = blockIdx.x;            // mask index
    int lane = threadIdx.x & 63;
    int wv = threadIdx.x >> 6;     // wave id 0..3
    for (int it = 0; it < 64; ++it) {
        int w = it * 4 + wv;       // word index 0..255
        int p = w * 64 + lane;     // pixel
        float v = seg[(size_t)i * HW + p];
        unsigned long long m = __ballot(v > 0.5f);
        if (lane == 0) packed[w * NM + i] = m;
    }
}

__global__ __launch_bounds__(256) void diou_kernel(const unsigned long long* __restrict__ packed,
                                                   const int* __restrict__ labels,
                                                   float* __restrict__ diou) {
    __shared__ unsigned long long wi[WORDS];
    int i = blockIdx.x;
    int j = threadIdx.x;
    wi[j] = packed[j * NM + i];
    __syncthreads();
    int inter = 0, si = 0, sj = 0;
    for (int w = 0; w < WORDS; ++w) {
        unsigned long long a = wi[w];
        unsigned long long b = packed[w * NM + j];
        inter += __popcll(a & b);
        si += __popcll(a);
        sj += __popcll(b);
    }
    float d = 0.0f;
    if (j > i && labels[i] == labels[j]) {
        float u = (float)(si + sj - inter);   // exact integers in f32
        d = (float)inter / u;
    }
    diou[i * NM + j] = d;
}

__global__ __launch_bounds__(256) void nms_finish_kernel(const float* __restrict__ diou,
                                                         const float* __restrict__ scores_in,
                                                         float* __restrict__ out) {
    #pragma clang fp contract(off)
    __shared__ float compm[NM];
    int j = threadIdx.x;
    float comp = 0.0f;
    for (int i = 0; i < NM; ++i) comp = fmaxf(comp, diou[i * NM + j]);
    float t = comp * comp;
    compm[j] = expf(-2.0f * t);
    __syncthreads();
    float coef = 3.0e38f;
    for (int i = 0; i < NM; ++i) {
        float d = diou[i * NM + j];
        float dd = d * d;
        float dec = expf(-2.0f * dd);
        float r = dec / compm[i];
        coef = fminf(coef, r);
    }
    out[j] = scores_in[j] * coef;
}

// ---------------- CRF ----------------
// State byte per pixel: bit0 = s1 (ret1==0.55), bit1 = s0 (ret0==0.55), bit2 = target.

__global__ __launch_bounds__(256) void crf_init_kernel(const float* __restrict__ x,
                                                       const float* __restrict__ targets,
                                                       unsigned char* __restrict__ state) {
    #pragma clang fp contract(off)
    int idx = blockIdx.x * 256 + threadIdx.x;
    float xv = x[idx];
    float tv = targets[idx];
    float xt = xv * tv;
    int b1 = (xt > 0.5f) ? 1 : 0;
    unsigned char st = (unsigned char)(b1 | ((b1 ^ 1) << 1) | ((tv > 0.5f ? 1 : 0) << 2));
    state[idx] = st;
}

// Precompute kernel weights: crfk[b][k][p], matching reference op order exactly.
__global__ __launch_bounds__(256) void crfw_kernel(const float* __restrict__ feat,
                                                   float* __restrict__ crfk) {
    #pragma clang fp contract(off)
    int idx = blockIdx.x * 256 + threadIdx.x;
    int b = idx >> 14;
    int p = idx & (HW - 1);
    int y = p >> 7, x = p & 127;
    const float* f = feat + (size_t)b * 3 * HW;
    float c0 = f[p] + 10.0f;
    float c1 = f[HW + p] + 10.0f;
    float c2 = f[2 * HW + p] + 10.0f;
    for (int k = 0; k < 9; ++k) {
        int dy = k / 3 - 1, dx = k % 3 - 1;
        int yy = y + dy, xx = x + dx;
        float u0 = 0.0f, u1 = 0.0f, u2 = 0.0f;
        if ((unsigned)yy < 128u && (unsigned)xx < 128u) {
            int q = yy * 128 + xx;
            u0 = f[q] + 10.0f;
            u1 = f[HW + q] + 10.0f;
            u2 = f[2 * HW + q] + 10.0f;
        }
        float d0 = u0 - c0, d1 = u1 - c1, d2 = u2 - c2;
        float ss = d0 * d0;
        ss = ss + d1 * d1;
        ss = ss + d2 * d2;
        float color = (-ss) / 0.5f;                       // -sum / (2*theta0^2)
        float sp = (float)(dy * dy + dx * dx) / 1800.0f;  // spatial / (2*theta1^2)
        crfk[((size_t)b * 9 + k) * HW + p] = 3.0f * expf(color - sp);
    }
}

template <bool FLY>
__global__ __launch_bounds__(256) void crf_iter_kernel(const unsigned char* __restrict__ sIn,
                                                       unsigned char* __restrict__ sOut,
                                                       const float* __restrict__ crfk,
                                                       const float* __restrict__ feat) {
    #pragma clang fp contract(off)
    int idx = blockIdx.x * 256 + threadIdx.x;
    int b = idx >> 14, p = idx & (HW - 1);
    int y = p >> 7, x = p & 127;
    const float l45 = 0.7985076962177716f;  // -log(0.45f)
    const float l55 = 0.5978370007556204f;  // -log(0.55f)
    float aggre0 = 0.0f, aggre1 = 0.0f;
    const float* f = feat + (size_t)b * 3 * HW;
    float c0 = 0.0f, c1 = 0.0f, c2 = 0.0f;
    if constexpr (FLY) {
        c0 = f[p] + 10.0f;
        c1 = f[HW + p] + 10.0f;
        c2 = f[2 * HW + p] + 10.0f;
    }
    for (int k = 0; k < 9; ++k) {
        int dy = k / 3 - 1, dx = k % 3 - 1;
        int yy = y + dy, xx = x + dx;
        if ((unsigned)yy < 128u && (unsigned)xx < 128u) {
            int q = yy * 128 + xx;
            float kw;
            if constexpr (FLY) {
                float u0 = f[q] + 10.0f, u1 = f[HW + q] + 10.0f, u2 = f[2 * HW + q] + 10.0f;
                float d0 = u0 - c0, d1 = u1 - c1, d2 = u2 - c2;
                float ss = d0 * d0;
                ss = ss + d1 * d1;
                ss = ss + d2 * d2;
                float color = (-ss) / 0.5f;
                float sp = (float)(dy * dy + dx * dx) / 1800.0f;
                kw = 3.0f * expf(color - sp);
            } else {
                kw = crfk[((size_t)b * 9 + k) * HW + p];
            }
            unsigned char sq = sIn[(size_t)b * HW + q];
            float lx1 = (sq & 1) ? l55 : l45;
            float lx0 = (sq & 2) ? l55 : l45;
            float t1 = lx1 * kw;   // separate mul then add (numpy: multiply, then sum)
            float t0 = lx0 * kw;
            aggre1 = aggre1 + t1;
            aggre0 = aggre0 + t0;
        }
        // OOB: uf_x == 0 from zero padding -> term is exactly 0; skip is identical.
    }
    unsigned char sc = sIn[(size_t)b * HW + p];
    float tval = (sc & 4) ? 1.0f : 0.0f;
    float e1 = expf(-aggre1);
    float e0 = expf(-aggre0);
    float m1 = e1 * tval;          // f * [ones, targets]
    float f1 = m1 + 1e-6f;         // f + 1e-6
    float f0 = e0 + 1e-6f;
    float den = f0 + f1;           // sum over channel axis: f0 + f1
    float r1 = f1 / den;
    float r0 = f0 / den;
    int s1 = (r1 > 0.5f) ? 1 : 0;
    int s0 = (r0 > 0.5f) ? 1 : 0;
    sOut[(size_t)b * HW + p] = (unsigned char)(s1 | (s0 << 1) | (sc & 4));
}

__global__ __launch_bounds__(256) void masks_out_kernel(const unsigned char* __restrict__ s,
                                                        float* __restrict__ outMasks) {
    int idx = blockIdx.x * 256 + threadIdx.x;
    outMasks[idx] = (s[idx] & 1) ? 1.0f : 0.0f;
}

__global__ __launch_bounds__(256) void valid_kernel(const unsigned char* __restrict__ s,
                                                    float* __restrict__ outValid) {
    __shared__ int red[256];
    int b = blockIdx.x, t = threadIdx.x;
    int cnt = 0;
    for (int k = 0; k < 64; ++k) cnt += (s[(size_t)b * HW + k * 256 + t] & 1);
    red[t] = cnt;
    __syncthreads();
    for (int off = 128; off > 0; off >>= 1) {
        if (t < off) red[t] += red[t + off];
        __syncthreads();
    }
    // count >= 16384*0.05 (=819.2) && <= 16384*0.95 (=15564.8); counts are integers
    if (t == 0) outValid[b] = (red[0] >= 820 && red[0] <= 15564) ? 1.0f : 0.0f;
}

extern "C" void kernel_launch(void* const* d_in, const int* in_sizes, int n_in,
                              void* d_out, int out_size, void* d_ws, size_t ws_size,
                              hipStream_t stream) {
    const float* seg = (const float*)d_in[0];
    const float* cate_scores = (const float*)d_in[1];
    const float* feat = (const float*)d_in[2];
    const float* x = (const float*)d_in[3];
    const float* targets = (const float*)d_in[4];
    const int* labels = (const int*)d_in[5];
    float* out = (float*)d_out;
    char* ws = (char*)d_ws;

    unsigned char* stateA = (unsigned char*)ws;                       // 1 MB
    unsigned char* stateB = stateA + (size_t)NI * HW;                 // 1 MB
    unsigned long long* packed = (unsigned long long*)(ws + 2u * NI * HW);         // 512 KB
    float* diou = (float*)(ws + 2u * NI * HW + (size_t)WORDS * NM * 8);            // 256 KB
    size_t crfkOff = 3u * 1024u * 1024u;
    float* crfk = (float*)(ws + crfkOff);
    bool useBuf = ws_size >= crfkOff + (size_t)NI * 9 * HW * 4;

    // --- Matrix NMS ---
    pack_kernel<<<NM, 256, 0, stream>>>(seg, packed);
    diou_kernel<<<NM, 256, 0, stream>>>(packed, labels, diou);
    nms_finish_kernel<<<1, 256, 0, stream>>>(diou, cate_scores, out);

    // --- CRF ---
    int nb = (NI * HW) / 256;  // 4096 blocks
    crf_init_kernel<<<nb, 256, 0, stream>>>(x, targets, stateA);
    if (useBuf) crfw_kernel<<<nb, 256, 0, stream>>>(feat, crfk);

    unsigned char* sIn = stateA;
    unsigned char* sOut = stateB;
    for (int it = 0; it < 10; ++it) {
        if (useBuf)
            crf_iter_kernel<false><<<nb, 256, 0, stream>>>(sIn, sOut, crfk, feat);
        else
            crf_iter_kernel<true><<<nb, 256, 0, stream>>>(sIn, sOut, nullptr, feat);
        unsigned char* tmp = sIn; sIn = sOut; sOut = tmp;
    }

    masks_out_kernel<<<nb, 256, 0, stream>>>(sIn, out + NM);
    valid_kernel<<<NI, 256, 0, stream>>>(sIn, out + NM + (size_t)NI * HW);
}

// Round 2
// 244.482 us; speedup vs baseline: 1.3169x; 1.3169x over previous
//
#include <hip/hip_runtime.h>
#include <stdint.h>

#define HH 128
#define WW 128
#define HW 16384
#define NI 64
#define NM 256
#define WORDS 256  // 16384 / 64 bits

// ---------------- Matrix NMS ----------------

// Pack binary masks into bits: packed[word][mask] layout for coalesced column reads.
__global__ __launch_bounds__(256) void pack_kernel(const float* __restrict__ seg,
                                                   unsigned long long* __restrict__ packed) {
    int i = blockIdx.x;            // mask index
    int lane = threadIdx.x & 63;
    int wv = threadIdx.x >> 6;     // wave id 0..3
    for (int it = 0; it < 64; ++it) {
        int w = it * 4 + wv;       // word index 0..255
        int p = w * 64 + lane;     // pixel
        float v = seg[(size_t)i * HW + p];
        unsigned long long m = __ballot(v > 0.5f);
        if (lane == 0) packed[w * NM + i] = m;
    }
}

__global__ __launch_bounds__(256) void diou_kernel(const unsigned long long* __restrict__ packed,
                                                   const int* __restrict__ labels,
                                                   float* __restrict__ diou) {
    __shared__ unsigned long long wi[WORDS];
    int i = blockIdx.x;
    int j = threadIdx.x;
    wi[j] = packed[j * NM + i];
    __syncthreads();
    int inter = 0, si = 0, sj = 0;
    for (int w = 0; w < WORDS; ++w) {
        unsigned long long a = wi[w];
        unsigned long long b = packed[w * NM + j];
        inter += __popcll(a & b);
        si += __popcll(a);
        sj += __popcll(b);
    }
    float d = 0.0f;
    if (j > i && labels[i] == labels[j]) {
        float u = (float)(si + sj - inter);   // exact integers in f32
        d = (float)inter / u;
    }
    diou[i * NM + j] = d;
}

// compm[j] = exp(-2 * (max_i diou[i][j])^2) — max is order-independent, safe to tree-reduce.
__global__ __launch_bounds__(256) void compm_kernel(const float* __restrict__ diou,
                                                    float* __restrict__ compm) {
    #pragma clang fp contract(off)
    __shared__ float red[NM];
    int j = blockIdx.x, i = threadIdx.x;
    red[i] = diou[i * NM + j];
    __syncthreads();
    for (int off = 128; off > 0; off >>= 1) {
        if (i < off) red[i] = fmaxf(red[i], red[i + off]);
        __syncthreads();
    }
    if (i == 0) {
        float m = red[0];
        float t = m * m;
        compm[j] = expf(-2.0f * t);
    }
}

// out[j] = scores[j] * min_i( exp(-2*diou[i][j]^2) / compm[i] ) — min order-independent.
__global__ __launch_bounds__(256) void coef_kernel(const float* __restrict__ diou,
                                                   const float* __restrict__ compm,
                                                   const float* __restrict__ scores_in,
                                                   float* __restrict__ out) {
    #pragma clang fp contract(off)
    __shared__ float red[NM];
    int j = blockIdx.x, i = threadIdx.x;
    float d = diou[i * NM + j];
    float dd = d * d;
    float dec = expf(-2.0f * dd);
    red[i] = dec / compm[i];
    __syncthreads();
    for (int off = 128; off > 0; off >>= 1) {
        if (i < off) red[i] = fminf(red[i], red[i + off]);
        __syncthreads();
    }
    if (i == 0) out[j] = scores_in[j] * red[0];
}

// ---------------- CRF ----------------
// State byte per pixel: bit0 = s1 (ret1==0.55), bit1 = s0 (ret0==0.55), bit2 = target.

// Fused: init state byte + precompute kernel weights crfk[b][k][p] (reference op order).
__global__ __launch_bounds__(256) void crf_setup_kernel(const float* __restrict__ x,
                                                        const float* __restrict__ targets,
                                                        const float* __restrict__ feat,
                                                        unsigned char* __restrict__ state,
                                                        float* __restrict__ crfk) {
    #pragma clang fp contract(off)
    int idx = blockIdx.x * 256 + threadIdx.x;
    // --- init ---
    float xv = x[idx];
    float tv = targets[idx];
    float xt = xv * tv;
    int b1 = (xt > 0.5f) ? 1 : 0;
    state[idx] = (unsigned char)(b1 | ((b1 ^ 1) << 1) | ((tv > 0.5f ? 1 : 0) << 2));
    // --- weights ---
    int b = idx >> 14;
    int p = idx & (HW - 1);
    int y = p >> 7, xc = p & 127;
    const float* f = feat + (size_t)b * 3 * HW;
    float c0 = f[p] + 10.0f;
    float c1 = f[HW + p] + 10.0f;
    float c2 = f[2 * HW + p] + 10.0f;
    for (int k = 0; k < 9; ++k) {
        int dy = k / 3 - 1, dx = k % 3 - 1;
        int yy = y + dy, xx = xc + dx;
        float u0 = 0.0f, u1 = 0.0f, u2 = 0.0f;
        if ((unsigned)yy < 128u && (unsigned)xx < 128u) {
            int q = yy * 128 + xx;
            u0 = f[q] + 10.0f;
            u1 = f[HW + q] + 10.0f;
            u2 = f[2 * HW + q] + 10.0f;
        }
        float d0 = u0 - c0, d1 = u1 - c1, d2 = u2 - c2;
        float ss = d0 * d0;
        ss = ss + d1 * d1;
        ss = ss + d2 * d2;
        float color = (-ss) / 0.5f;                       // -sum / (2*theta0^2)
        float sp = (float)(dy * dy + dx * dx) / 1800.0f;  // spatial / (2*theta1^2)
        crfk[((size_t)b * 9 + k) * HW + p] = 3.0f * expf(color - sp);
    }
}

__global__ __launch_bounds__(256) void crf_iter_kernel(const unsigned char* __restrict__ sIn,
                                                       unsigned char* __restrict__ sOut,
                                                       const float* __restrict__ crfk) {
    #pragma clang fp contract(off)
    int idx = blockIdx.x * 256 + threadIdx.x;
    int b = idx >> 14, p = idx & (HW - 1);
    int y = p >> 7, x = p & 127;
    const float l45 = 0.7985076962177716f;  // -log(0.45f)
    const float l55 = 0.5978370007556204f;  // -log(0.55f)
    float aggre0 = 0.0f, aggre1 = 0.0f;
    for (int k = 0; k < 9; ++k) {
        int dy = k / 3 - 1, dx = k % 3 - 1;
        int yy = y + dy, xx = x + dx;
        if ((unsigned)yy < 128u && (unsigned)xx < 128u) {
            int q = yy * 128 + xx;
            float kw = crfk[((size_t)b * 9 + k) * HW + p];
            unsigned char sq = sIn[(size_t)b * HW + q];
            float lx1 = (sq & 1) ? l55 : l45;
            float lx0 = (sq & 2) ? l55 : l45;
            float t1 = lx1 * kw;   // separate mul then add (numpy: multiply, then sum)
            float t0 = lx0 * kw;
            aggre1 = aggre1 + t1;
            aggre0 = aggre0 + t0;
        }
        // OOB: uf_x == 0 from zero padding -> term is exactly 0; skip is identical.
    }
    unsigned char sc = sIn[(size_t)b * HW + p];
    float tval = (sc & 4) ? 1.0f : 0.0f;
    float e1 = expf(-aggre1);
    float e0 = expf(-aggre0);
    float m1 = e1 * tval;          // f * [ones, targets]
    float f1 = m1 + 1e-6f;         // f + 1e-6
    float f0 = e0 + 1e-6f;
    float den = f0 + f1;           // sum over channel axis: f0 + f1
    float r1 = f1 / den;
    float r0 = f0 / den;
    int s1 = (r1 > 0.5f) ? 1 : 0;
    int s0 = (r0 > 0.5f) ? 1 : 0;
    sOut[(size_t)b * HW + p] = (unsigned char)(s1 | (s0 << 1) | (sc & 4));
}

// Fused: write masks + per-image count + validity.
__global__ __launch_bounds__(256) void tail_kernel(const unsigned char* __restrict__ s,
                                                   float* __restrict__ outMasks,
                                                   float* __restrict__ outValid) {
    __shared__ int red[256];
    int b = blockIdx.x, t = threadIdx.x;
    int cnt = 0;
    for (int k = 0; k < 64; ++k) {
        int p = k * 256 + t;
        int v = s[(size_t)b * HW + p] & 1;
        outMasks[(size_t)b * HW + p] = (float)v;
        cnt += v;
    }
    red[t] = cnt;
    __syncthreads();
    for (int off = 128; off > 0; off >>= 1) {
        if (t < off) red[t] += red[t + off];
        __syncthreads();
    }
    // count >= 16384*0.05 (=819.2) && <= 16384*0.95 (=15564.8); counts are integers
    if (t == 0) outValid[b] = (red[0] >= 820 && red[0] <= 15564) ? 1.0f : 0.0f;
}

extern "C" void kernel_launch(void* const* d_in, const int* in_sizes, int n_in,
                              void* d_out, int out_size, void* d_ws, size_t ws_size,
                              hipStream_t stream) {
    const float* seg = (const float*)d_in[0];
    const float* cate_scores = (const float*)d_in[1];
    const float* feat = (const float*)d_in[2];
    const float* x = (const float*)d_in[3];
    const float* targets = (const float*)d_in[4];
    const int* labels = (const int*)d_in[5];
    float* out = (float*)d_out;
    char* ws = (char*)d_ws;

    unsigned char* stateA = (unsigned char*)ws;                       // 1 MB
    unsigned char* stateB = stateA + (size_t)NI * HW;                 // 1 MB
    unsigned long long* packed = (unsigned long long*)(ws + 2u * NI * HW);         // 512 KB
    float* diou = (float*)(ws + 2u * NI * HW + (size_t)WORDS * NM * 8);            // 256 KB
    float* compm = diou + (size_t)NM * NM;                                         // 1 KB
    size_t crfkOff = 3u * 1024u * 1024u;
    float* crfk = (float*)(ws + crfkOff);                             // 36 MB

    // --- Matrix NMS ---
    pack_kernel<<<NM, 256, 0, stream>>>(seg, packed);
    diou_kernel<<<NM, 256, 0, stream>>>(packed, labels, diou);
    compm_kernel<<<NM, 256, 0, stream>>>(diou, compm);
    coef_kernel<<<NM, 256, 0, stream>>>(diou, compm, cate_scores, out);

    // --- CRF ---
    int nb = (NI * HW) / 256;  // 4096 blocks
    crf_setup_kernel<<<nb, 256, 0, stream>>>(x, targets, feat, stateA, crfk);

    unsigned char* sIn = stateA;
    unsigned char* sOut = stateB;
    for (int it = 0; it < 10; ++it) {
        crf_iter_kernel<<<nb, 256, 0, stream>>>(sIn, sOut, crfk);
        unsigned char* tmp = sIn; sIn = sOut; sOut = tmp;
    }

    tail_kernel<<<NI, 256, 0, stream>>>(sIn, out + NM, out + NM + (size_t)NI * HW);
}